// Round 2
// baseline (822.268 us; speedup 1.0000x reference)
//
#include <hip/hip_runtime.h>
#include <hip/hip_bf16.h>

typedef __attribute__((ext_vector_type(8))) short  short8;
typedef __attribute__((ext_vector_type(4))) short  short4v;
typedef __attribute__((ext_vector_type(8))) __bf16 bf16x8;
typedef __attribute__((ext_vector_type(4))) float  f32x4;

#define DEVI static __device__ __forceinline__

constexpr int B_  = 8;
constexpr int L_  = 2048;
constexpr int S_  = 2048;
constexpr int DK  = 512;    // H*E = H*D = 512
constexpr int KVB = 32;     // keys per iteration
constexpr int QB  = 64;     // q rows per block (4 waves x 16)
constexpr float SCL2 = 0.125f * 1.4426950408889634f;  // (1/sqrt(E)) * log2(e)

DEVI short f2bf(float f) {
  __hip_bfloat16 h = __float2bfloat16(f);
  return __builtin_bit_cast(short, h);
}

__global__ __launch_bounds__(256, 2)
void fattn_kernel(const float* __restrict__ Qg, const float* __restrict__ Kg,
                  const float* __restrict__ Vg, const unsigned char* __restrict__ Mg,
                  float* __restrict__ Og) {
  // K tile: [kv][e] bf16, row = 1024B, swizzled byte ^= (row&7)<<4
  __shared__ __attribute__((aligned(16))) short kbuf[KVB * DK];
  // V tile transposed (d-major), paired rows: row = d>>1 (256 rows x 128B),
  // col byte = (d&1)*64 + kv*2, swizzled byte ^= ((d>>1)&7)<<4
  __shared__ __attribute__((aligned(16))) short vbuf[KVB * DK];
  // P per wave: [16 q][32 kv] bf16 (64B rows)
  __shared__ __attribute__((aligned(16))) short pbuf[4][16 * KVB];

  const int tid = threadIdx.x;
  const int w   = tid >> 6;
  const int l   = tid & 63;
  const int l15 = l & 15;
  const int l4  = l >> 4;

  const int b    = blockIdx.y;
  const int qloc = blockIdx.x * QB + w * 16;   // this wave's q-row base (within batch)

  // ---------------- Q fragments (A operand: row = l15, k = c*32 + l4*8 + j) ----
  bf16x8 qf[16];
  {
    const float* qp = Qg + ((size_t)(b * L_ + qloc + l15)) * DK + l4 * 8;
    #pragma unroll
    for (int c = 0; c < 16; ++c) {
      float4 a  = *(const float4*)(qp + c * 32);
      float4 bq = *(const float4*)(qp + c * 32 + 4);
      short8 f;
      f[0] = f2bf(a.x);  f[1] = f2bf(a.y);  f[2] = f2bf(a.z);  f[3] = f2bf(a.w);
      f[4] = f2bf(bq.x); f[5] = f2bf(bq.y); f[6] = f2bf(bq.z); f[7] = f2bf(bq.w);
      qf[c] = __builtin_bit_cast(bf16x8, f);
    }
  }

  f32x4 acc[32];
  #pragma unroll
  for (int i = 0; i < 32; ++i) acc[i] = f32x4{0.f, 0.f, 0.f, 0.f};
  float mrow[4] = {-__builtin_inff(), -__builtin_inff(), -__builtin_inff(), -__builtin_inff()};
  float lrow[4] = {0.f, 0.f, 0.f, 0.f};

  const float* Kb = Kg + (size_t)b * S_ * DK;
  const float* Vb = Vg + (size_t)b * S_ * DK;
  const unsigned char* Mb = Mg + (size_t)b * L_ * S_;

  // hoisted fragment byte-bases (K base kept UNSWIZZLED; XOR applied after +c*64
  // to avoid the bit-6 carry bug: swz bit6 collides with c*64)
  const int bKu  = (l15 << 10) + (l4 << 4);
  const int swzK = (l15 & 7) << 4;
  const int bV = (((l15 >> 1) << 7) + ((l15 & 1) << 6) + (l4 << 4)) ^ (((l15 >> 1) & 7) << 4);
  const int bP = l15 * 64 + l4 * 16;

  for (int t = 0; t < S_ / KVB; ++t) {
    const int k0 = t * KVB;

    // ---------------- stage K tile (linear flat, coalesced float4) -------------
    {
      const float* src = Kb + (size_t)k0 * DK;
      #pragma unroll
      for (int it = 0; it < 16; ++it) {
        int fidx = it * 1024 + tid * 4;
        float4 v = *(const float4*)(src + fidx);
        int row = fidx >> 9;
        int col = fidx & 511;
        int byt = ((row << 10) + (col << 1)) ^ ((row & 7) << 4);
        short4v pk = { f2bf(v.x), f2bf(v.y), f2bf(v.z), f2bf(v.w) };
        *(short4v*)((char*)kbuf + byt) = pk;
      }
    }
    // ---------------- stage V tile transposed (per-thread 4x4 transpose) -------
    {
      const float* src = Vb + (size_t)k0 * DK;
      #pragma unroll
      for (int h = 0; h < 4; ++h) {
        int task = h * 256 + tid;
        int dblk = task & 127;     // d block of 4
        int kvb  = task >> 7;      // kv block of 4
        const float* sp = src + (size_t)(kvb * 4) * DK + dblk * 4;
        float4 r0 = *(const float4*)(sp);
        float4 r1 = *(const float4*)(sp + DK);
        float4 r2 = *(const float4*)(sp + 2 * DK);
        float4 r3 = *(const float4*)(sp + 3 * DK);
        #pragma unroll
        for (int i = 0; i < 4; ++i) {
          int d = dblk * 4 + i;
          int byt = (((d >> 1) << 7) + ((d & 1) << 6) + ((kvb * 4) << 1))
                    ^ (((d >> 1) & 7) << 4);
          float e0 = (i == 0) ? r0.x : (i == 1) ? r0.y : (i == 2) ? r0.z : r0.w;
          float e1 = (i == 0) ? r1.x : (i == 1) ? r1.y : (i == 2) ? r1.z : r1.w;
          float e2 = (i == 0) ? r2.x : (i == 1) ? r2.y : (i == 2) ? r2.z : r2.w;
          float e3 = (i == 0) ? r3.x : (i == 1) ? r3.y : (i == 2) ? r3.z : r3.w;
          short4v pk = { f2bf(e0), f2bf(e1), f2bf(e2), f2bf(e3) };
          *(short4v*)((char*)vbuf + byt) = pk;
        }
      }
    }
    __syncthreads();

    // ---------------- QK^T : S[16 q][32 kv], 4 independent MFMA chains ---------
    f32x4 s0a = f32x4{0.f, 0.f, 0.f, 0.f};
    f32x4 s0b = f32x4{0.f, 0.f, 0.f, 0.f};
    f32x4 s1a = f32x4{0.f, 0.f, 0.f, 0.f};
    f32x4 s1b = f32x4{0.f, 0.f, 0.f, 0.f};
    #pragma unroll
    for (int c = 0; c < 16; c += 2) {
      int a0 = (bKu + c * 64) ^ swzK;
      int a1 = (bKu + (c + 1) * 64) ^ swzK;
      bf16x8 k0f = *(const bf16x8*)((const char*)kbuf + a0);
      bf16x8 k0g = *(const bf16x8*)((const char*)kbuf + a1);
      bf16x8 k1f = *(const bf16x8*)((const char*)kbuf + a0 + 16384);
      bf16x8 k1g = *(const bf16x8*)((const char*)kbuf + a1 + 16384);
      s0a = __builtin_amdgcn_mfma_f32_16x16x32_bf16(qf[c],     k0f, s0a, 0, 0, 0);
      s1a = __builtin_amdgcn_mfma_f32_16x16x32_bf16(qf[c],     k1f, s1a, 0, 0, 0);
      s0b = __builtin_amdgcn_mfma_f32_16x16x32_bf16(qf[c + 1], k0g, s0b, 0, 0, 0);
      s1b = __builtin_amdgcn_mfma_f32_16x16x32_bf16(qf[c + 1], k1g, s1b, 0, 0, 0);
    }
    f32x4 s0, s1;
    #pragma unroll
    for (int r = 0; r < 4; ++r) { s0[r] = s0a[r] + s0b[r]; s1[r] = s1a[r] + s1b[r]; }

    // ---------------- mask + online softmax (deferred rescale) -----------------
    float sv0[4], sv1[4];
    #pragma unroll
    for (int r = 0; r < 4; ++r) {
      const unsigned char* mp = Mb + (size_t)(qloc + l4 * 4 + r) * S_ + (k0 + l15);
      float x0 = s0[r], x1 = s1[r];
      if (mp[0])  x0 = -__builtin_inff();
      if (mp[16]) x1 = -__builtin_inff();
      sv0[r] = x0; sv1[r] = x1;
    }

    bool need = false;
    float alpha[4];
    #pragma unroll
    for (int r = 0; r < 4; ++r) {
      float tmax = fmaxf(sv0[r], sv1[r]);
      #pragma unroll
      for (int mk = 1; mk < 16; mk <<= 1) tmax = fmaxf(tmax, __shfl_xor(tmax, mk));
      alpha[r] = 1.0f;
      if (tmax > mrow[r]) {
        if ((tmax - mrow[r]) * SCL2 > 8.0f) {   // defer small max-growth (T13)
          alpha[r] = exp2f((mrow[r] - tmax) * SCL2);
          mrow[r] = tmax;
          need = true;
        }
      }
    }
    if (__any(need)) {
      #pragma unroll
      for (int dt = 0; dt < 32; ++dt) {
        acc[dt][0] *= alpha[0];
        acc[dt][1] *= alpha[1];
        acc[dt][2] *= alpha[2];
        acc[dt][3] *= alpha[3];
      }
      lrow[0] *= alpha[0]; lrow[1] *= alpha[1];
      lrow[2] *= alpha[2]; lrow[3] *= alpha[3];
    }

    // P = exp2((s - m)*scale*log2e), bf16, via per-wave LDS relayout (D -> A frag)
    short* pw = pbuf[w];
    #pragma unroll
    for (int r = 0; r < 4; ++r) {
      float p0 = exp2f((sv0[r] - mrow[r]) * SCL2);
      float p1 = exp2f((sv1[r] - mrow[r]) * SCL2);
      lrow[r] += p0 + p1;
      int pr = (l4 * 4 + r) * 32;
      pw[pr + l15]      = f2bf(p0);
      pw[pr + 16 + l15] = f2bf(p1);
    }
    bf16x8 pf = *(const bf16x8*)((const char*)pw + bP);

    // ---------------- PV : acc[16 q][512 d] += P * V ---------------------------
    #pragma unroll
    for (int dt = 0; dt < 32; ++dt) {
      bf16x8 vf = *(const bf16x8*)((const char*)vbuf + (bV + dt * 1024));
      acc[dt] = __builtin_amdgcn_mfma_f32_16x16x32_bf16(pf, vf, acc[dt], 0, 0, 0);
    }
    __syncthreads();
  }

  // ---------------- epilogue: normalize + store --------------------------------
  #pragma unroll
  for (int r = 0; r < 4; ++r) {
    float s = lrow[r];
    #pragma unroll
    for (int mk = 1; mk < 16; mk <<= 1) s += __shfl_xor(s, mk);
    lrow[r] = 1.0f / s;
  }
  float* op = Og + ((size_t)(b * L_ + qloc + l4 * 4)) * DK + l15;
  #pragma unroll
  for (int r = 0; r < 4; ++r) {
    #pragma unroll
    for (int dt = 0; dt < 32; ++dt) {
      op[(size_t)r * DK + dt * 16] = acc[dt][r] * lrow[r];
    }
  }
}

extern "C" void kernel_launch(void* const* d_in, const int* in_sizes, int n_in,
                              void* d_out, int out_size, void* d_ws, size_t ws_size,
                              hipStream_t stream) {
  const float* Q = (const float*)d_in[0];
  const float* K = (const float*)d_in[1];
  const float* V = (const float*)d_in[2];
  const unsigned char* M = (const unsigned char*)d_in[3];
  float* O = (float*)d_out;
  dim3 grid(L_ / QB, B_);
  fattn_kernel<<<grid, 256, 0, stream>>>(Q, K, V, M, O);
}

// Round 3
// 224.825 us; speedup vs baseline: 3.6574x; 3.6574x over previous
//
#include <hip/hip_runtime.h>
#include <hip/hip_bf16.h>
#include <stdint.h>

typedef __attribute__((ext_vector_type(8))) short  short8;
typedef __attribute__((ext_vector_type(4))) short  short4v;
typedef __attribute__((ext_vector_type(8))) __bf16 bf16x8;
typedef __attribute__((ext_vector_type(4))) float  f32x4;

#define DEVI static __device__ __forceinline__

constexpr int B_  = 8;
constexpr int L_  = 2048;
constexpr int S_  = 2048;
constexpr int DK  = 512;    // H*E = H*D = 512
constexpr int KVB = 32;     // keys per tile
constexpr int QB  = 64;     // q rows per block (4 waves x 16)
constexpr int NT  = S_ / KVB;            // 64 tiles
constexpr int TILE_B = KVB * DK * 2;     // 32768 bytes per bf16 tile image
constexpr float SCL2 = 0.125f * 1.4426950408889634f;  // (1/sqrt(E)) * log2(e)

// ws layout
constexpr size_t KT_OFF = 0;
constexpr size_t VT_OFF = (size_t)B_ * NT * TILE_B;            // 16,777,216
constexpr size_t AM_OFF = VT_OFF * 2;                          // 33,554,432
constexpr size_t WS_NEED = AM_OFF + (size_t)B_ * L_ * 8;       // + 131,072

DEVI short f2bf(float f) {
  __hip_bfloat16 h = __float2bfloat16(f);
  return __builtin_bit_cast(short, h);
}

DEVI void gld16(const void* g, void* l) {
  // global -> LDS DMA, 16B per lane; LDS dest must be wave-uniform base.
  __builtin_amdgcn_global_load_lds(
      (const __attribute__((address_space(1))) unsigned int*)(uintptr_t)g,
      (__attribute__((address_space(3))) unsigned int*)(uint32_t)(uintptr_t)l,
      16, 0, 0);
}

// ============================ pre-pass kernels ================================

// K tiles: ws image = swizzled LDS kbuf content. byte in tile o:
//   row = o>>10 (kv), unswizzled col byte = (o&1023) ^ ((row&7)<<4)
__global__ __launch_bounds__(256)
void prep_k(const float* __restrict__ K, char* __restrict__ Kt) {
  int gid  = blockIdx.x * 256 + threadIdx.x;   // 1,048,576 threads
  int o    = (gid & 2047) * 16;                // 16B chunk within 32KB tile
  int tile = gid >> 11;                        // b*64 + t  (512 tiles)
  int row  = o >> 10;
  int colb = (o & 1023) ^ ((row & 7) << 4);
  const float* src = K + ((size_t)tile * KVB + row) * DK + (colb >> 1);
  float4 a = ((const float4*)src)[0];
  float4 c = ((const float4*)src)[1];
  short8 f;
  f[0] = f2bf(a.x); f[1] = f2bf(a.y); f[2] = f2bf(a.z); f[3] = f2bf(a.w);
  f[4] = f2bf(c.x); f[5] = f2bf(c.y); f[6] = f2bf(c.z); f[7] = f2bf(c.w);
  *(short8*)(Kt + (size_t)tile * TILE_B + o) = f;
}

// V tiles: ws image = swizzled, d-major (transposed) LDS vbuf content.
// forward: byt = ((d>>1)<<7) + ((d&1)<<6) + kv*2, then ^ ((d>>1)&7)<<4
__global__ __launch_bounds__(256)
void prep_v(const float* __restrict__ V, char* __restrict__ Vt) {
  __shared__ short lv[KVB * DK];   // 32KB linear [kv][d] bf16
  int tile = blockIdx.x;           // b*64 + t
  int tid  = threadIdx.x;
  const float* src = V + (size_t)tile * KVB * DK;
  #pragma unroll
  for (int i = 0; i < 16; ++i) {
    int fidx = i * 1024 + tid * 4;
    float4 v = *(const float4*)(src + fidx);
    short4v pk = { f2bf(v.x), f2bf(v.y), f2bf(v.z), f2bf(v.w) };
    *(short4v*)((char*)lv + (size_t)fidx * 2) = pk;
  }
  __syncthreads();
  char* dst = Vt + (size_t)tile * TILE_B;
  #pragma unroll
  for (int j = 0; j < 8; ++j) {
    int o     = tid * 16 + j * 4096;
    int pr    = o >> 7;
    int inner = (o & 127) ^ ((pr & 7) << 4);
    int d     = pr * 2 + (inner >> 6);
    int kv0   = (inner & 63) >> 1;
    short8 f;
    #pragma unroll
    for (int k = 0; k < 8; ++k) f[k] = lv[(kv0 + k) * DK + d];
    *(short8*)(dst + o) = f;
  }
}

// mask bitmap: bit t of anyM[b*L + row] = any(mask[b, row, t*32 .. t*32+31])
__global__ __launch_bounds__(256)
void prep_mask(const unsigned char* __restrict__ M,
               unsigned long long* __restrict__ anyM) {
  int row = blockIdx.x * 4 + (threadIdx.x >> 6);
  int l   = threadIdx.x & 63;
  const unsigned int* p = (const unsigned int*)(M + (size_t)row * S_) + l * 8;
  unsigned int acc = 0;
  #pragma unroll
  for (int k = 0; k < 8; ++k) acc |= p[k];
  unsigned long long bal = __ballot(acc != 0);
  if (l == 0) anyM[row] = bal;
}

// ============================ hot attention kernel ============================

__global__ __launch_bounds__(256, 1)
void fattn2(const float* __restrict__ Qg, const char* __restrict__ Kt,
            const char* __restrict__ Vt, const unsigned long long* __restrict__ anyM,
            const unsigned char* __restrict__ Mg, float* __restrict__ Og) {
  __shared__ __attribute__((aligned(16))) char kv_lds[2][2 * TILE_B];  // K|V per buf
  __shared__ __attribute__((aligned(16))) short pbuf[4][16 * KVB];

  const int tid = threadIdx.x;
  const int w   = tid >> 6;
  const int l   = tid & 63;
  const int l15 = l & 15;
  const int l4  = l >> 4;

  // XCD-aware swizzle: batch b lands entirely on one XCD (K/V tiles ~4.2MB ~ L2)
  const int bidx = blockIdx.x;
  const int swz  = ((bidx & 7) << 5) + (bidx >> 3);
  const int b    = swz >> 5;
  const int qt   = swz & 31;
  const int qloc = qt * QB + w * 16;

  // ---------------- Q fragments (A operand: row=l15, k = c*32 + l4*8 + j) -----
  bf16x8 qf[16];
  {
    const float* qp = Qg + ((size_t)(b * L_ + qloc + l15)) * DK + l4 * 8;
    #pragma unroll
    for (int c = 0; c < 16; ++c) {
      float4 a  = *(const float4*)(qp + c * 32);
      float4 bq = *(const float4*)(qp + c * 32 + 4);
      short8 f;
      f[0] = f2bf(a.x);  f[1] = f2bf(a.y);  f[2] = f2bf(a.z);  f[3] = f2bf(a.w);
      f[4] = f2bf(bq.x); f[5] = f2bf(bq.y); f[6] = f2bf(bq.z); f[7] = f2bf(bq.w);
      qf[c] = __builtin_bit_cast(bf16x8, f);
    }
  }
  const unsigned long long mbits = anyM[(size_t)b * L_ + qloc + l15];

  f32x4 acc[32];
  #pragma unroll
  for (int i = 0; i < 32; ++i) acc[i] = f32x4{0.f, 0.f, 0.f, 0.f};
  float mrow[4] = {-__builtin_inff(), -__builtin_inff(), -__builtin_inff(), -__builtin_inff()};
  float lrow[4] = {0.f, 0.f, 0.f, 0.f};

  const char* Ktb = Kt + (size_t)b * NT * TILE_B;
  const char* Vtb = Vt + (size_t)b * NT * TILE_B;
  const unsigned char* Mb = Mg + (size_t)b * L_ * S_;

  // fragment byte-bases (XOR applied after all sub-row adds; carries checked)
  const int bKu  = (l15 << 10) + (l4 << 4);
  const int swzK = (l15 & 7) << 4;
  const int bV = (((l15 >> 1) << 7) + ((l15 & 1) << 6) + (l4 << 4)) ^ (((l15 >> 1) & 7) << 4);
  const int bP = l15 * 64 + l4 * 16;

  // ---------------- staging helper: 16 x 16B DMA per thread per tile ----------
  auto stage = [&](int t, char* buf) {
    const char* ks = Ktb + (size_t)t * TILE_B + w * 1024 + l * 16;
    const char* vs = Vtb + (size_t)t * TILE_B + w * 1024 + l * 16;
    char* kd = buf + w * 1024;            // wave-uniform LDS base (+lane*16 by HW)
    char* vd = buf + TILE_B + w * 1024;
    #pragma unroll
    for (int r = 0; r < 8; ++r) gld16(ks + r * 4096, kd + r * 4096);
    #pragma unroll
    for (int r = 0; r < 8; ++r) gld16(vs + r * 4096, vd + r * 4096);
  };

  stage(0, kv_lds[0]);
  stage(1, kv_lds[1]);

  for (int t = 0; t < NT; ++t) {
    // wait own tile-t loads (leave tile-t+1's 16 in flight), then barrier:
    // every wave has waited its own -> tile t fully resident.
    if (t < NT - 1) asm volatile("s_waitcnt vmcnt(16)" ::: "memory");
    else            asm volatile("s_waitcnt vmcnt(0)"  ::: "memory");
    __builtin_amdgcn_s_barrier();
    asm volatile("" ::: "memory");

    const char* kb = kv_lds[t & 1];
    const char* vb = kv_lds[t & 1] + TILE_B;

    // ---------------- QK^T : S[16 q][32 kv], 4 independent MFMA chains --------
    f32x4 s0a = f32x4{0.f, 0.f, 0.f, 0.f};
    f32x4 s0b = f32x4{0.f, 0.f, 0.f, 0.f};
    f32x4 s1a = f32x4{0.f, 0.f, 0.f, 0.f};
    f32x4 s1b = f32x4{0.f, 0.f, 0.f, 0.f};
    #pragma unroll
    for (int c = 0; c < 16; c += 2) {
      int a0 = (bKu + c * 64) ^ swzK;
      int a1 = (bKu + (c + 1) * 64) ^ swzK;
      bf16x8 k0f = *(const bf16x8*)(kb + a0);
      bf16x8 k0g = *(const bf16x8*)(kb + a1);
      bf16x8 k1f = *(const bf16x8*)(kb + a0 + 16384);
      bf16x8 k1g = *(const bf16x8*)(kb + a1 + 16384);
      s0a = __builtin_amdgcn_mfma_f32_16x16x32_bf16(qf[c],     k0f, s0a, 0, 0, 0);
      s1a = __builtin_amdgcn_mfma_f32_16x16x32_bf16(qf[c],     k1f, s1a, 0, 0, 0);
      s0b = __builtin_amdgcn_mfma_f32_16x16x32_bf16(qf[c + 1], k0g, s0b, 0, 0, 0);
      s1b = __builtin_amdgcn_mfma_f32_16x16x32_bf16(qf[c + 1], k1g, s1b, 0, 0, 0);
    }
    float sv0[4], sv1[4];
    #pragma unroll
    for (int r = 0; r < 4; ++r) { sv0[r] = s0a[r] + s0b[r]; sv1[r] = s1a[r] + s1b[r]; }

    // ---------------- mask (bitmap fast path) ---------------------------------
    if (__any((mbits >> t) & 1ull)) {
      #pragma unroll
      for (int r = 0; r < 4; ++r) {
        const unsigned char* mp = Mb + (size_t)(qloc + l4 * 4 + r) * S_ + (t * KVB + l15);
        if (mp[0])  sv0[r] = -__builtin_inff();
        if (mp[16]) sv1[r] = -__builtin_inff();
      }
    }

    // ---------------- online softmax (deferred rescale, T13) ------------------
    bool need = false;
    float alpha[4];
    #pragma unroll
    for (int r = 0; r < 4; ++r) {
      float tmax = fmaxf(sv0[r], sv1[r]);
      #pragma unroll
      for (int mk = 1; mk < 16; mk <<= 1) tmax = fmaxf(tmax, __shfl_xor(tmax, mk));
      alpha[r] = 1.0f;
      if (tmax > mrow[r]) {
        if ((tmax - mrow[r]) * SCL2 > 8.0f) {
          alpha[r] = exp2f((mrow[r] - tmax) * SCL2);
          mrow[r] = tmax;
          need = true;
        }
      }
    }
    if (__any(need)) {
      #pragma unroll
      for (int dt = 0; dt < 32; ++dt) {
        acc[dt][0] *= alpha[0];
        acc[dt][1] *= alpha[1];
        acc[dt][2] *= alpha[2];
        acc[dt][3] *= alpha[3];
      }
      lrow[0] *= alpha[0]; lrow[1] *= alpha[1];
      lrow[2] *= alpha[2]; lrow[3] *= alpha[3];
    }

    // P = exp2((s-m)*scl), bf16, per-wave LDS relayout (D-frag -> A-frag)
    short* pw = pbuf[w];
    #pragma unroll
    for (int r = 0; r < 4; ++r) {
      float p0 = exp2f((sv0[r] - mrow[r]) * SCL2);
      float p1 = exp2f((sv1[r] - mrow[r]) * SCL2);
      lrow[r] += p0 + p1;
      int pr = (l4 * 4 + r) * 32;
      pw[pr + l15]      = f2bf(p0);
      pw[pr + 16 + l15] = f2bf(p1);
    }
    bf16x8 pf = *(const bf16x8*)((const char*)pw + bP);

    // ---------------- PV : acc[16 q][512 d] += P * V ---------------------------
    #pragma unroll
    for (int dt = 0; dt < 32; ++dt) {
      bf16x8 vf = *(const bf16x8*)(vb + bV + dt * 1024);
      acc[dt] = __builtin_amdgcn_mfma_f32_16x16x32_bf16(pf, vf, acc[dt], 0, 0, 0);
    }

    asm volatile("" ::: "memory");
    __builtin_amdgcn_s_barrier();   // all waves done reading buf[t&1]
    if (t + 2 < NT) stage(t + 2, kv_lds[t & 1]);
  }

  // ---------------- epilogue: normalize + store --------------------------------
  #pragma unroll
  for (int r = 0; r < 4; ++r) {
    float s = lrow[r];
    #pragma unroll
    for (int mk = 1; mk < 16; mk <<= 1) s += __shfl_xor(s, mk);
    lrow[r] = 1.0f / s;
  }
  float* op = Og + ((size_t)(b * L_ + qloc + l4 * 4)) * DK + l15;
  #pragma unroll
  for (int r = 0; r < 4; ++r) {
    #pragma unroll
    for (int dt = 0; dt < 32; ++dt) {
      op[(size_t)r * DK + dt * 16] = acc[dt][r] * lrow[r];
    }
  }
}

// ============================ fallback (round-2 kernel) =======================

__global__ __launch_bounds__(256, 2)
void fattn_kernel(const float* __restrict__ Qg, const float* __restrict__ Kg,
                  const float* __restrict__ Vg, const unsigned char* __restrict__ Mg,
                  float* __restrict__ Og) {
  __shared__ __attribute__((aligned(16))) short kbuf[KVB * DK];
  __shared__ __attribute__((aligned(16))) short vbuf[KVB * DK];
  __shared__ __attribute__((aligned(16))) short pbuf[4][16 * KVB];

  const int tid = threadIdx.x;
  const int w   = tid >> 6;
  const int l   = tid & 63;
  const int l15 = l & 15;
  const int l4  = l >> 4;

  const int b    = blockIdx.y;
  const int qloc = blockIdx.x * QB + w * 16;

  bf16x8 qf[16];
  {
    const float* qp = Qg + ((size_t)(b * L_ + qloc + l15)) * DK + l4 * 8;
    #pragma unroll
    for (int c = 0; c < 16; ++c) {
      float4 a  = *(const float4*)(qp + c * 32);
      float4 bq = *(const float4*)(qp + c * 32 + 4);
      short8 f;
      f[0] = f2bf(a.x);  f[1] = f2bf(a.y);  f[2] = f2bf(a.z);  f[3] = f2bf(a.w);
      f[4] = f2bf(bq.x); f[5] = f2bf(bq.y); f[6] = f2bf(bq.z); f[7] = f2bf(bq.w);
      qf[c] = __builtin_bit_cast(bf16x8, f);
    }
  }

  f32x4 acc[32];
  #pragma unroll
  for (int i = 0; i < 32; ++i) acc[i] = f32x4{0.f, 0.f, 0.f, 0.f};
  float mrow[4] = {-__builtin_inff(), -__builtin_inff(), -__builtin_inff(), -__builtin_inff()};
  float lrow[4] = {0.f, 0.f, 0.f, 0.f};

  const float* Kb = Kg + (size_t)b * S_ * DK;
  const float* Vb = Vg + (size_t)b * S_ * DK;
  const unsigned char* Mb = Mg + (size_t)b * L_ * S_;

  const int bKu  = (l15 << 10) + (l4 << 4);
  const int swzK = (l15 & 7) << 4;
  const int bV = (((l15 >> 1) << 7) + ((l15 & 1) << 6) + (l4 << 4)) ^ (((l15 >> 1) & 7) << 4);
  const int bP = l15 * 64 + l4 * 16;

  for (int t = 0; t < S_ / KVB; ++t) {
    const int k0 = t * KVB;
    {
      const float* src = Kb + (size_t)k0 * DK;
      #pragma unroll
      for (int it = 0; it < 16; ++it) {
        int fidx = it * 1024 + tid * 4;
        float4 v = *(const float4*)(src + fidx);
        int row = fidx >> 9;
        int col = fidx & 511;
        int byt = ((row << 10) + (col << 1)) ^ ((row & 7) << 4);
        short4v pk = { f2bf(v.x), f2bf(v.y), f2bf(v.z), f2bf(v.w) };
        *(short4v*)((char*)kbuf + byt) = pk;
      }
    }
    {
      const float* src = Vb + (size_t)k0 * DK;
      #pragma unroll
      for (int h = 0; h < 4; ++h) {
        int task = h * 256 + tid;
        int dblk = task & 127;
        int kvb  = task >> 7;
        const float* sp = src + (size_t)(kvb * 4) * DK + dblk * 4;
        float4 r0 = *(const float4*)(sp);
        float4 r1 = *(const float4*)(sp + DK);
        float4 r2 = *(const float4*)(sp + 2 * DK);
        float4 r3 = *(const float4*)(sp + 3 * DK);
        #pragma unroll
        for (int i = 0; i < 4; ++i) {
          int d = dblk * 4 + i;
          int byt = (((d >> 1) << 7) + ((d & 1) << 6) + ((kvb * 4) << 1))
                    ^ (((d >> 1) & 7) << 4);
          float e0 = (i == 0) ? r0.x : (i == 1) ? r0.y : (i == 2) ? r0.z : r0.w;
          float e1 = (i == 0) ? r1.x : (i == 1) ? r1.y : (i == 2) ? r1.z : r1.w;
          float e2 = (i == 0) ? r2.x : (i == 1) ? r2.y : (i == 2) ? r2.z : r2.w;
          float e3 = (i == 0) ? r3.x : (i == 1) ? r3.y : (i == 2) ? r3.z : r3.w;
          short4v pk = { f2bf(e0), f2bf(e1), f2bf(e2), f2bf(e3) };
          *(short4v*)((char*)vbuf + byt) = pk;
        }
      }
    }
    __syncthreads();

    f32x4 s0a = f32x4{0.f, 0.f, 0.f, 0.f};
    f32x4 s0b = f32x4{0.f, 0.f, 0.f, 0.f};
    f32x4 s1a = f32x4{0.f, 0.f, 0.f, 0.f};
    f32x4 s1b = f32x4{0.f, 0.f, 0.f, 0.f};
    #pragma unroll
    for (int c = 0; c < 16; c += 2) {
      int a0 = (bKu + c * 64) ^ swzK;
      int a1 = (bKu + (c + 1) * 64) ^ swzK;
      bf16x8 k0f = *(const bf16x8*)((const char*)kbuf + a0);
      bf16x8 k0g = *(const bf16x8*)((const char*)kbuf + a1);
      bf16x8 k1f = *(const bf16x8*)((const char*)kbuf + a0 + 16384);
      bf16x8 k1g = *(const bf16x8*)((const char*)kbuf + a1 + 16384);
      s0a = __builtin_amdgcn_mfma_f32_16x16x32_bf16(qf[c],     k0f, s0a, 0, 0, 0);
      s1a = __builtin_amdgcn_mfma_f32_16x16x32_bf16(qf[c],     k1f, s1a, 0, 0, 0);
      s0b = __builtin_amdgcn_mfma_f32_16x16x32_bf16(qf[c + 1], k0g, s0b, 0, 0, 0);
      s1b = __builtin_amdgcn_mfma_f32_16x16x32_bf16(qf[c + 1], k1g, s1b, 0, 0, 0);
    }
    f32x4 s0, s1;
    #pragma unroll
    for (int r = 0; r < 4; ++r) { s0[r] = s0a[r] + s0b[r]; s1[r] = s1a[r] + s1b[r]; }

    float sv0[4], sv1[4];
    #pragma unroll
    for (int r = 0; r < 4; ++r) {
      const unsigned char* mp = Mb + (size_t)(qloc + l4 * 4 + r) * S_ + (k0 + l15);
      float x0 = s0[r], x1 = s1[r];
      if (mp[0])  x0 = -__builtin_inff();
      if (mp[16]) x1 = -__builtin_inff();
      sv0[r] = x0; sv1[r] = x1;
    }

    bool need = false;
    float alpha[4];
    #pragma unroll
    for (int r = 0; r < 4; ++r) {
      float tmax = fmaxf(sv0[r], sv1[r]);
      #pragma unroll
      for (int mk = 1; mk < 16; mk <<= 1) tmax = fmaxf(tmax, __shfl_xor(tmax, mk));
      alpha[r] = 1.0f;
      if (tmax > mrow[r]) {
        if ((tmax - mrow[r]) * SCL2 > 8.0f) {
          alpha[r] = exp2f((mrow[r] - tmax) * SCL2);
          mrow[r] = tmax;
          need = true;
        }
      }
    }
    if (__any(need)) {
      #pragma unroll
      for (int dt = 0; dt < 32; ++dt) {
        acc[dt][0] *= alpha[0];
        acc[dt][1] *= alpha[1];
        acc[dt][2] *= alpha[2];
        acc[dt][3] *= alpha[3];
      }
      lrow[0] *= alpha[0]; lrow[1] *= alpha[1];
      lrow[2] *= alpha[2]; lrow[3] *= alpha[3];
    }

    short* pw = pbuf[w];
    #pragma unroll
    for (int r = 0; r < 4; ++r) {
      float p0 = exp2f((sv0[r] - mrow[r]) * SCL2);
      float p1 = exp2f((sv1[r] - mrow[r]) * SCL2);
      lrow[r] += p0 + p1;
      int pr = (l4 * 4 + r) * 32;
      pw[pr + l15]      = f2bf(p0);
      pw[pr + 16 + l15] = f2bf(p1);
    }
    bf16x8 pf = *(const bf16x8*)((const char*)pw + bP);

    #pragma unroll
    for (int dt = 0; dt < 32; ++dt) {
      bf16x8 vf = *(const bf16x8*)((const char*)vbuf + (bV + dt * 1024));
      acc[dt] = __builtin_amdgcn_mfma_f32_16x16x32_bf16(pf, vf, acc[dt], 0, 0, 0);
    }
    __syncthreads();
  }

  #pragma unroll
  for (int r = 0; r < 4; ++r) {
    float s = lrow[r];
    #pragma unroll
    for (int mk = 1; mk < 16; mk <<= 1) s += __shfl_xor(s, mk);
    lrow[r] = 1.0f / s;
  }
  float* op = Og + ((size_t)(b * L_ + qloc + l4 * 4)) * DK + l15;
  #pragma unroll
  for (int r = 0; r < 4; ++r) {
    #pragma unroll
    for (int dt = 0; dt < 32; ++dt) {
      op[(size_t)r * DK + dt * 16] = acc[dt][r] * lrow[r];
    }
  }
}

// ============================ launch ==========================================

extern "C" void kernel_launch(void* const* d_in, const int* in_sizes, int n_in,
                              void* d_out, int out_size, void* d_ws, size_t ws_size,
                              hipStream_t stream) {
  const float* Q = (const float*)d_in[0];
  const float* K = (const float*)d_in[1];
  const float* V = (const float*)d_in[2];
  const unsigned char* M = (const unsigned char*)d_in[3];
  float* O = (float*)d_out;

  if (ws_size >= WS_NEED) {
    char* ws = (char*)d_ws;
    prep_k   <<<4096, 256, 0, stream>>>(K, ws + KT_OFF);
    prep_v   <<<B_ * NT, 256, 0, stream>>>(V, ws + VT_OFF);
    prep_mask<<<B_ * L_ / 4, 256, 0, stream>>>(M, (unsigned long long*)(ws + AM_OFF));
    fattn2   <<<256, 256, 0, stream>>>(Q, ws + KT_OFF, ws + VT_OFF,
                                       (const unsigned long long*)(ws + AM_OFF), M, O);
  } else {
    dim3 grid(L_ / QB, B_);
    fattn_kernel<<<grid, 256, 0, stream>>>(Q, K, V, M, O);
  }
}

// Round 4
// 224.561 us; speedup vs baseline: 3.6617x; 1.0012x over previous
//
#include <hip/hip_runtime.h>
#include <hip/hip_bf16.h>
#include <stdint.h>

typedef __attribute__((ext_vector_type(8))) short  short8;
typedef __attribute__((ext_vector_type(4))) short  short4v;
typedef __attribute__((ext_vector_type(8))) __bf16 bf16x8;
typedef __attribute__((ext_vector_type(4))) float  f32x4;

#define DEVI static __device__ __forceinline__

constexpr int B_  = 8;
constexpr int L_  = 2048;
constexpr int S_  = 2048;
constexpr int DK  = 512;    // H*E = H*D = 512
constexpr int KVB = 32;     // keys per tile
constexpr int QB  = 64;     // q rows per block (4 waves x 16)
constexpr int NT  = S_ / KVB;            // 64 tiles
constexpr int TILE_B = KVB * DK * 2;     // 32768 bytes per bf16 tile image
constexpr float SCL2 = 0.125f * 1.4426950408889634f;  // (1/sqrt(E)) * log2(e)

// ws layout
constexpr size_t KT_OFF = 0;
constexpr size_t VT_OFF = (size_t)B_ * NT * TILE_B;            // 16,777,216
constexpr size_t AM_OFF = VT_OFF * 2;                          // 33,554,432
constexpr size_t WS_NEED = AM_OFF + (size_t)B_ * L_ * 8;       // + 131,072

DEVI short f2bf(float f) {
  __hip_bfloat16 h = __float2bfloat16(f);
  return __builtin_bit_cast(short, h);
}

DEVI void gld16(const void* g, void* l) {
  // global -> LDS DMA, 16B per lane; LDS dest must be wave-uniform base.
  __builtin_amdgcn_global_load_lds(
      (const __attribute__((address_space(1))) unsigned int*)(uintptr_t)g,
      (__attribute__((address_space(3))) unsigned int*)(uint32_t)(uintptr_t)l,
      16, 0, 0);
}

// ============================ pre-pass kernels ================================

// K tiles: ws image = swizzled LDS kbuf content. byte in tile o:
//   row = o>>10 (kv), unswizzled col byte = (o&1023) ^ ((row&7)<<4)
__global__ __launch_bounds__(256)
void prep_k(const float* __restrict__ K, char* __restrict__ Kt) {
  int gid  = blockIdx.x * 256 + threadIdx.x;   // 1,048,576 threads
  int o    = (gid & 2047) * 16;                // 16B chunk within 32KB tile
  int tile = gid >> 11;                        // b*64 + t  (512 tiles)
  int row  = o >> 10;
  int colb = (o & 1023) ^ ((row & 7) << 4);
  const float* src = K + ((size_t)tile * KVB + row) * DK + (colb >> 1);
  float4 a = ((const float4*)src)[0];
  float4 c = ((const float4*)src)[1];
  short8 f;
  f[0] = f2bf(a.x); f[1] = f2bf(a.y); f[2] = f2bf(a.z); f[3] = f2bf(a.w);
  f[4] = f2bf(c.x); f[5] = f2bf(c.y); f[6] = f2bf(c.z); f[7] = f2bf(c.w);
  *(short8*)(Kt + (size_t)tile * TILE_B + o) = f;
}

// V tiles: ws image = swizzled, d-major (transposed) LDS vbuf content.
// forward: byt = ((d>>1)<<7) + ((d&1)<<6) + kv*2, then ^ ((d>>1)&7)<<4
__global__ __launch_bounds__(256)
void prep_v(const float* __restrict__ V, char* __restrict__ Vt) {
  __shared__ short lv[KVB * DK];   // 32KB linear [kv][d] bf16
  int tile = blockIdx.x;           // b*64 + t
  int tid  = threadIdx.x;
  const float* src = V + (size_t)tile * KVB * DK;
  #pragma unroll
  for (int i = 0; i < 16; ++i) {
    int fidx = i * 1024 + tid * 4;
    float4 v = *(const float4*)(src + fidx);
    short4v pk = { f2bf(v.x), f2bf(v.y), f2bf(v.z), f2bf(v.w) };
    *(short4v*)((char*)lv + (size_t)fidx * 2) = pk;
  }
  __syncthreads();
  char* dst = Vt + (size_t)tile * TILE_B;
  #pragma unroll
  for (int j = 0; j < 8; ++j) {
    int o     = tid * 16 + j * 4096;
    int pr    = o >> 7;
    int inner = (o & 127) ^ ((pr & 7) << 4);
    int d     = pr * 2 + (inner >> 6);
    int kv0   = (inner & 63) >> 1;
    short8 f;
    #pragma unroll
    for (int k = 0; k < 8; ++k) f[k] = lv[(kv0 + k) * DK + d];
    *(short8*)(dst + o) = f;
  }
}

// mask bitmap: bit t of anyM[b*L + row] = any(mask[b, row, t*32 .. t*32+31])
__global__ __launch_bounds__(256)
void prep_mask(const unsigned char* __restrict__ M,
               unsigned long long* __restrict__ anyM) {
  int row = blockIdx.x * 4 + (threadIdx.x >> 6);
  int l   = threadIdx.x & 63;
  const unsigned int* p = (const unsigned int*)(M + (size_t)row * S_) + l * 8;
  unsigned int acc = 0;
  #pragma unroll
  for (int k = 0; k < 8; ++k) acc |= p[k];
  unsigned long long bal = __ballot(acc != 0);
  if (l == 0) anyM[row] = bal;
}

// ============================ hot attention kernel ============================

__global__ __launch_bounds__(256, 1)
void fattn2(const float* __restrict__ Qg, const char* __restrict__ Kt,
            const char* __restrict__ Vt, const unsigned long long* __restrict__ anyM,
            const unsigned char* __restrict__ Mg, float* __restrict__ Og) {
  __shared__ __attribute__((aligned(16))) char kv_lds[2][2 * TILE_B];  // K|V per buf
  __shared__ __attribute__((aligned(16))) short pbuf[4][16 * KVB];

  const int tid = threadIdx.x;
  const int w   = tid >> 6;
  const int l   = tid & 63;
  const int l15 = l & 15;
  const int l4  = l >> 4;

  // XCD-aware swizzle: batch b lands entirely on one XCD (K/V tiles ~4.2MB ~ L2)
  const int bidx = blockIdx.x;
  const int swz  = ((bidx & 7) << 5) + (bidx >> 3);
  const int b    = swz >> 5;
  const int qt   = swz & 31;
  const int qloc = qt * QB + w * 16;

  // ---------------- Q fragments (A operand: row=l15, k = c*32 + l4*8 + j) -----
  bf16x8 qf[16];
  {
    const float* qp = Qg + ((size_t)(b * L_ + qloc + l15)) * DK + l4 * 8;
    #pragma unroll
    for (int c = 0; c < 16; ++c) {
      float4 a  = *(const float4*)(qp + c * 32);
      float4 bq = *(const float4*)(qp + c * 32 + 4);
      short8 f;
      f[0] = f2bf(a.x);  f[1] = f2bf(a.y);  f[2] = f2bf(a.z);  f[3] = f2bf(a.w);
      f[4] = f2bf(bq.x); f[5] = f2bf(bq.y); f[6] = f2bf(bq.z); f[7] = f2bf(bq.w);
      qf[c] = __builtin_bit_cast(bf16x8, f);
    }
  }
  const unsigned long long mbits = anyM[(size_t)b * L_ + qloc + l15];

  f32x4 acc[32];
  #pragma unroll
  for (int i = 0; i < 32; ++i) acc[i] = f32x4{0.f, 0.f, 0.f, 0.f};
  float mrow[4] = {-__builtin_inff(), -__builtin_inff(), -__builtin_inff(), -__builtin_inff()};
  float lrow[4] = {0.f, 0.f, 0.f, 0.f};

  const char* Ktb = Kt + (size_t)b * NT * TILE_B;
  const char* Vtb = Vt + (size_t)b * NT * TILE_B;
  const unsigned char* Mb = Mg + (size_t)b * L_ * S_;

  // fragment byte-bases (XOR applied after all sub-row adds; carries checked)
  const int bKu  = (l15 << 10) + (l4 << 4);
  const int swzK = (l15 & 7) << 4;
  const int bV = (((l15 >> 1) << 7) + ((l15 & 1) << 6) + (l4 << 4)) ^ (((l15 >> 1) & 7) << 4);
  const int bP = l15 * 64 + l4 * 16;

  // ---------------- staging helper: 16 x 16B DMA per thread per tile ----------
  auto stage = [&](int t, char* buf) {
    const char* ks = Ktb + (size_t)t * TILE_B + w * 1024 + l * 16;
    const char* vs = Vtb + (size_t)t * TILE_B + w * 1024 + l * 16;
    char* kd = buf + w * 1024;            // wave-uniform LDS base (+lane*16 by HW)
    char* vd = buf + TILE_B + w * 1024;
    #pragma unroll
    for (int r = 0; r < 8; ++r) gld16(ks + r * 4096, kd + r * 4096);
    #pragma unroll
    for (int r = 0; r < 8; ++r) gld16(vs + r * 4096, vd + r * 4096);
  };

  stage(0, kv_lds[0]);
  stage(1, kv_lds[1]);

  for (int t = 0; t < NT; ++t) {
    // wait own tile-t loads (leave tile-t+1's 16 in flight), then barrier:
    // every wave has waited its own -> tile t fully resident.
    if (t < NT - 1) asm volatile("s_waitcnt vmcnt(16)" ::: "memory");
    else            asm volatile("s_waitcnt vmcnt(0)"  ::: "memory");
    __builtin_amdgcn_s_barrier();
    asm volatile("" ::: "memory");

    const char* kb = kv_lds[t & 1];
    const char* vb = kv_lds[t & 1] + TILE_B;

    // ---------------- QK^T : S[16 q][32 kv], 4 independent MFMA chains --------
    f32x4 s0a = f32x4{0.f, 0.f, 0.f, 0.f};
    f32x4 s0b = f32x4{0.f, 0.f, 0.f, 0.f};
    f32x4 s1a = f32x4{0.f, 0.f, 0.f, 0.f};
    f32x4 s1b = f32x4{0.f, 0.f, 0.f, 0.f};
    #pragma unroll
    for (int c = 0; c < 16; c += 2) {
      int a0 = (bKu + c * 64) ^ swzK;
      int a1 = (bKu + (c + 1) * 64) ^ swzK;
      bf16x8 k0f = *(const bf16x8*)(kb + a0);
      bf16x8 k0g = *(const bf16x8*)(kb + a1);
      bf16x8 k1f = *(const bf16x8*)(kb + a0 + 16384);
      bf16x8 k1g = *(const bf16x8*)(kb + a1 + 16384);
      s0a = __builtin_amdgcn_mfma_f32_16x16x32_bf16(qf[c],     k0f, s0a, 0, 0, 0);
      s1a = __builtin_amdgcn_mfma_f32_16x16x32_bf16(qf[c],     k1f, s1a, 0, 0, 0);
      s0b = __builtin_amdgcn_mfma_f32_16x16x32_bf16(qf[c + 1], k0g, s0b, 0, 0, 0);
      s1b = __builtin_amdgcn_mfma_f32_16x16x32_bf16(qf[c + 1], k1g, s1b, 0, 0, 0);
    }
    float sv0[4], sv1[4];
    #pragma unroll
    for (int r = 0; r < 4; ++r) { sv0[r] = s0a[r] + s0b[r]; sv1[r] = s1a[r] + s1b[r]; }

    // ---------------- mask (bitmap fast path) ---------------------------------
    if (__any((mbits >> t) & 1ull)) {
      #pragma unroll
      for (int r = 0; r < 4; ++r) {
        const unsigned char* mp = Mb + (size_t)(qloc + l4 * 4 + r) * S_ + (t * KVB + l15);
        if (mp[0])  sv0[r] = -__builtin_inff();
        if (mp[16]) sv1[r] = -__builtin_inff();
      }
    }

    // ---------------- online softmax (deferred rescale, T13) ------------------
    bool need = false;
    float alpha[4];
    #pragma unroll
    for (int r = 0; r < 4; ++r) {
      float tmax = fmaxf(sv0[r], sv1[r]);
      #pragma unroll
      for (int mk = 1; mk < 16; mk <<= 1) tmax = fmaxf(tmax, __shfl_xor(tmax, mk));
      alpha[r] = 1.0f;
      if (tmax > mrow[r]) {
        if ((tmax - mrow[r]) * SCL2 > 8.0f) {
          alpha[r] = exp2f((mrow[r] - tmax) * SCL2);
          mrow[r] = tmax;
          need = true;
        }
      }
    }
    if (__any(need)) {
      #pragma unroll
      for (int dt = 0; dt < 32; ++dt) {
        acc[dt][0] *= alpha[0];
        acc[dt][1] *= alpha[1];
        acc[dt][2] *= alpha[2];
        acc[dt][3] *= alpha[3];
      }
      lrow[0] *= alpha[0]; lrow[1] *= alpha[1];
      lrow[2] *= alpha[2]; lrow[3] *= alpha[3];
    }

    // P = exp2((s-m)*scl), bf16, per-wave LDS relayout (D-frag -> A-frag)
    short* pw = pbuf[w];
    #pragma unroll
    for (int r = 0; r < 4; ++r) {
      float p0 = exp2f((sv0[r] - mrow[r]) * SCL2);
      float p1 = exp2f((sv1[r] - mrow[r]) * SCL2);
      lrow[r] += p0 + p1;
      int pr = (l4 * 4 + r) * 32;
      pw[pr + l15]      = f2bf(p0);
      pw[pr + 16 + l15] = f2bf(p1);
    }
    bf16x8 pf = *(const bf16x8*)((const char*)pw + bP);

    // ---------------- PV : acc[16 q][512 d] += P * V ---------------------------
    #pragma unroll
    for (int dt = 0; dt < 32; ++dt) {
      bf16x8 vf = *(const bf16x8*)(vb + bV + dt * 1024);
      acc[dt] = __builtin_amdgcn_mfma_f32_16x16x32_bf16(pf, vf, acc[dt], 0, 0, 0);
    }

    asm volatile("" ::: "memory");
    __builtin_amdgcn_s_barrier();   // all waves done reading buf[t&1]
    if (t + 2 < NT) stage(t + 2, kv_lds[t & 1]);
  }

  // ---------------- epilogue: normalize + store --------------------------------
  #pragma unroll
  for (int r = 0; r < 4; ++r) {
    float s = lrow[r];
    #pragma unroll
    for (int mk = 1; mk < 16; mk <<= 1) s += __shfl_xor(s, mk);
    lrow[r] = 1.0f / s;
  }
  float* op = Og + ((size_t)(b * L_ + qloc + l4 * 4)) * DK + l15;
  #pragma unroll
  for (int r = 0; r < 4; ++r) {
    #pragma unroll
    for (int dt = 0; dt < 32; ++dt) {
      op[(size_t)r * DK + dt * 16] = acc[dt][r] * lrow[r];
    }
  }
}

// ============================ fallback (round-2 kernel) =======================

__global__ __launch_bounds__(256, 2)
void fattn_kernel(const float* __restrict__ Qg, const float* __restrict__ Kg,
                  const float* __restrict__ Vg, const unsigned char* __restrict__ Mg,
                  float* __restrict__ Og) {
  __shared__ __attribute__((aligned(16))) short kbuf[KVB * DK];
  __shared__ __attribute__((aligned(16))) short vbuf[KVB * DK];
  __shared__ __attribute__((aligned(16))) short pbuf[4][16 * KVB];

  const int tid = threadIdx.x;
  const int w   = tid >> 6;
  const int l   = tid & 63;
  const int l15 = l & 15;
  const int l4  = l >> 4;

  const int b    = blockIdx.y;
  const int qloc = blockIdx.x * QB + w * 16;

  bf16x8 qf[16];
  {
    const float* qp = Qg + ((size_t)(b * L_ + qloc + l15)) * DK + l4 * 8;
    #pragma unroll
    for (int c = 0; c < 16; ++c) {
      float4 a  = *(const float4*)(qp + c * 32);
      float4 bq = *(const float4*)(qp + c * 32 + 4);
      short8 f;
      f[0] = f2bf(a.x);  f[1] = f2bf(a.y);  f[2] = f2bf(a.z);  f[3] = f2bf(a.w);
      f[4] = f2bf(bq.x); f[5] = f2bf(bq.y); f[6] = f2bf(bq.z); f[7] = f2bf(bq.w);
      qf[c] = __builtin_bit_cast(bf16x8, f);
    }
  }

  f32x4 acc[32];
  #pragma unroll
  for (int i = 0; i < 32; ++i) acc[i] = f32x4{0.f, 0.f, 0.f, 0.f};
  float mrow[4] = {-__builtin_inff(), -__builtin_inff(), -__builtin_inff(), -__builtin_inff()};
  float lrow[4] = {0.f, 0.f, 0.f, 0.f};

  const float* Kb = Kg + (size_t)b * S_ * DK;
  const float* Vb = Vg + (size_t)b * S_ * DK;
  const unsigned char* Mb = Mg + (size_t)b * L_ * S_;

  const int bKu  = (l15 << 10) + (l4 << 4);
  const int swzK = (l15 & 7) << 4;
  const int bV = (((l15 >> 1) << 7) + ((l15 & 1) << 6) + (l4 << 4)) ^ (((l15 >> 1) & 7) << 4);
  const int bP = l15 * 64 + l4 * 16;

  for (int t = 0; t < S_ / KVB; ++t) {
    const int k0 = t * KVB;
    {
      const float* src = Kb + (size_t)k0 * DK;
      #pragma unroll
      for (int it = 0; it < 16; ++it) {
        int fidx = it * 1024 + tid * 4;
        float4 v = *(const float4*)(src + fidx);
        int row = fidx >> 9;
        int col = fidx & 511;
        int byt = ((row << 10) + (col << 1)) ^ ((row & 7) << 4);
        short4v pk = { f2bf(v.x), f2bf(v.y), f2bf(v.z), f2bf(v.w) };
        *(short4v*)((char*)kbuf + byt) = pk;
      }
    }
    {
      const float* src = Vb + (size_t)k0 * DK;
      #pragma unroll
      for (int h = 0; h < 4; ++h) {
        int task = h * 256 + tid;
        int dblk = task & 127;
        int kvb  = task >> 7;
        const float* sp = src + (size_t)(kvb * 4) * DK + dblk * 4;
        float4 r0 = *(const float4*)(sp);
        float4 r1 = *(const float4*)(sp + DK);
        float4 r2 = *(const float4*)(sp + 2 * DK);
        float4 r3 = *(const float4*)(sp + 3 * DK);
        #pragma unroll
        for (int i = 0; i < 4; ++i) {
          int d = dblk * 4 + i;
          int byt = (((d >> 1) << 7) + ((d & 1) << 6) + ((kvb * 4) << 1))
                    ^ (((d >> 1) & 7) << 4);
          float e0 = (i == 0) ? r0.x : (i == 1) ? r0.y : (i == 2) ? r0.z : r0.w;
          float e1 = (i == 0) ? r1.x : (i == 1) ? r1.y : (i == 2) ? r1.z : r1.w;
          float e2 = (i == 0) ? r2.x : (i == 1) ? r2.y : (i == 2) ? r2.z : r2.w;
          float e3 = (i == 0) ? r3.x : (i == 1) ? r3.y : (i == 2) ? r3.z : r3.w;
          short4v pk = { f2bf(e0), f2bf(e1), f2bf(e2), f2bf(e3) };
          *(short4v*)((char*)vbuf + byt) = pk;
        }
      }
    }
    __syncthreads();

    f32x4 s0a = f32x4{0.f, 0.f, 0.f, 0.f};
    f32x4 s0b = f32x4{0.f, 0.f, 0.f, 0.f};
    f32x4 s1a = f32x4{0.f, 0.f, 0.f, 0.f};
    f32x4 s1b = f32x4{0.f, 0.f, 0.f, 0.f};
    #pragma unroll
    for (int c = 0; c < 16; c += 2) {
      int a0 = (bKu + c * 64) ^ swzK;
      int a1 = (bKu + (c + 1) * 64) ^ swzK;
      bf16x8 k0f = *(const bf16x8*)((const char*)kbuf + a0);
      bf16x8 k0g = *(const bf16x8*)((const char*)kbuf + a1);
      bf16x8 k1f = *(const bf16x8*)((const char*)kbuf + a0 + 16384);
      bf16x8 k1g = *(const bf16x8*)((const char*)kbuf + a1 + 16384);
      s0a = __builtin_amdgcn_mfma_f32_16x16x32_bf16(qf[c],     k0f, s0a, 0, 0, 0);
      s1a = __builtin_amdgcn_mfma_f32_16x16x32_bf16(qf[c],     k1f, s1a, 0, 0, 0);
      s0b = __builtin_amdgcn_mfma_f32_16x16x32_bf16(qf[c + 1], k0g, s0b, 0, 0, 0);
      s1b = __builtin_amdgcn_mfma_f32_16x16x32_bf16(qf[c + 1], k1g, s1b, 0, 0, 0);
    }
    f32x4 s0, s1;
    #pragma unroll
    for (int r = 0; r < 4; ++r) { s0[r] = s0a[r] + s0b[r]; s1[r] = s1a[r] + s1b[r]; }

    float sv0[4], sv1[4];
    #pragma unroll
    for (int r = 0; r < 4; ++r) {
      const unsigned char* mp = Mb + (size_t)(qloc + l4 * 4 + r) * S_ + (k0 + l15);
      float x0 = s0[r], x1 = s1[r];
      if (mp[0])  x0 = -__builtin_inff();
      if (mp[16]) x1 = -__builtin_inff();
      sv0[r] = x0; sv1[r] = x1;
    }

    bool need = false;
    float alpha[4];
    #pragma unroll
    for (int r = 0; r < 4; ++r) {
      float tmax = fmaxf(sv0[r], sv1[r]);
      #pragma unroll
      for (int mk = 1; mk < 16; mk <<= 1) tmax = fmaxf(tmax, __shfl_xor(tmax, mk));
      alpha[r] = 1.0f;
      if (tmax > mrow[r]) {
        if ((tmax - mrow[r]) * SCL2 > 8.0f) {
          alpha[r] = exp2f((mrow[r] - tmax) * SCL2);
          mrow[r] = tmax;
          need = true;
        }
      }
    }
    if (__any(need)) {
      #pragma unroll
      for (int dt = 0; dt < 32; ++dt) {
        acc[dt][0] *= alpha[0];
        acc[dt][1] *= alpha[1];
        acc[dt][2] *= alpha[2];
        acc[dt][3] *= alpha[3];
      }
      lrow[0] *= alpha[0]; lrow[1] *= alpha[1];
      lrow[2] *= alpha[2]; lrow[3] *= alpha[3];
    }

    short* pw = pbuf[w];
    #pragma unroll
    for (int r = 0; r < 4; ++r) {
      float p0 = exp2f((sv0[r] - mrow[r]) * SCL2);
      float p1 = exp2f((sv1[r] - mrow[r]) * SCL2);
      lrow[r] += p0 + p1;
      int pr = (l4 * 4 + r) * 32;
      pw[pr + l15]      = f2bf(p0);
      pw[pr + 16 + l15] = f2bf(p1);
    }
    bf16x8 pf = *(const bf16x8*)((const char*)pw + bP);

    #pragma unroll
    for (int dt = 0; dt < 32; ++dt) {
      bf16x8 vf = *(const bf16x8*)((const char*)vbuf + (bV + dt * 1024));
      acc[dt] = __builtin_amdgcn_mfma_f32_16x16x32_bf16(pf, vf, acc[dt], 0, 0, 0);
    }
    __syncthreads();
  }

  #pragma unroll
  for (int r = 0; r < 4; ++r) {
    float s = lrow[r];
    #pragma unroll
    for (int mk = 1; mk < 16; mk <<= 1) s += __shfl_xor(s, mk);
    lrow[r] = 1.0f / s;
  }
  float* op = Og + ((size_t)(b * L_ + qloc + l4 * 4)) * DK + l15;
  #pragma unroll
  for (int r = 0; r < 4; ++r) {
    #pragma unroll
    for (int dt = 0; dt < 32; ++dt) {
      op[(size_t)r * DK + dt * 16] = acc[dt][r] * lrow[r];
    }
  }
}

// ============================ launch ==========================================

extern "C" void kernel_launch(void* const* d_in, const int* in_sizes, int n_in,
                              void* d_out, int out_size, void* d_ws, size_t ws_size,
                              hipStream_t stream) {
  const float* Q = (const float*)d_in[0];
  const float* K = (const float*)d_in[1];
  const float* V = (const float*)d_in[2];
  const unsigned char* M = (const unsigned char*)d_in[3];
  float* O = (float*)d_out;

  if (ws_size >= WS_NEED) {
    char* ws = (char*)d_ws;
    prep_k   <<<4096, 256, 0, stream>>>(K, ws + KT_OFF);
    prep_v   <<<B_ * NT, 256, 0, stream>>>(V, ws + VT_OFF);
    prep_mask<<<B_ * L_ / 4, 256, 0, stream>>>(M, (unsigned long long*)(ws + AM_OFF));
    fattn2   <<<256, 256, 0, stream>>>(Q, ws + KT_OFF, ws + VT_OFF,
                                       (const unsigned long long*)(ws + AM_OFF), M, O);
  } else {
    dim3 grid(L_ / QB, B_);
    fattn_kernel<<<grid, 256, 0, stream>>>(Q, K, V, M, O);
  }
}